// Round 7
// baseline (333.382 us; speedup 1.0000x reference)
//
#include <hip/hip_runtime.h>
#include <math.h>

#define NPTS 6890
#define BATCH 1024
#define FPB (NPTS * 3)   // 20670 floats per batch; 20670 % 4 == 2
#define FQ 5166          // full float4s per batch after 2-point alignment skip

// ---------------------------------------------------------------------------
// Fully fused kernel: one block per batch, 512 threads.
//   phase A: each thread loads 12 pred-float4s + 12 gt-float4s (kept in VGPRs
//            for the whole kernel -> inputs read from global EXACTLY ONCE),
//            accumulates 16 partial sums (means, |p|^2, cross-covariance).
//   block reduce -> 16 batch sums in LDS.
//   solve:   every thread redundantly runs the fp32 Procrustes solve (K^T K
//            Jacobi eigendecomp). Identical data -> exec-uniform branches; no
//            broadcast needed. Error contribution ~1e-5 (scale ~0.01
//            attenuates), far under the 0.108 threshold.
//   phase B: |scale*R*p + t - g| from cached registers, store.
// Rationale: R1-R6 showed read throughput is pinned at ~2.45 TB/s aggregate
// regardless of schedule/pattern/occupancy -> minimize bytes read (169 MB
// once instead of twice) and eliminate the extra kernel + gaps.
// ---------------------------------------------------------------------------

__device__ __forceinline__ void accum(float* acc, float p0, float p1, float p2,
                                      float g0, float g1, float g2) {
  acc[0] += p0;  acc[1] += p1;  acc[2] += p2;
  acc[3] += g0;  acc[4] += g1;  acc[5] += g2;
  acc[6] += p0 * p0 + p1 * p1 + p2 * p2;
  acc[7]  += p0 * g0;  acc[8]  += p0 * g1;  acc[9]  += p0 * g2;
  acc[10] += p1 * g0;  acc[11] += p1 * g1;  acc[12] += p1 * g2;
  acc[13] += p2 * g0;  acc[14] += p2 * g1;  acc[15] += p2 * g2;
}

__device__ __forceinline__ void accum_grp(float* acc, const float4 a0,
                                          const float4 a1, const float4 a2,
                                          const float4 c0, const float4 c1,
                                          const float4 c2) {
  accum(acc, a0.x, a0.y, a0.z, c0.x, c0.y, c0.z);
  accum(acc, a0.w, a1.x, a1.y, c0.w, c1.x, c1.y);
  accum(acc, a1.z, a1.w, a2.x, c1.z, c1.w, c2.x);
  accum(acc, a2.y, a2.z, a2.w, c2.y, c2.z, c2.w);
}

__device__ __forceinline__ void xform(const float* m, float p0, float p1,
                                      float p2, float g0, float g1, float g2,
                                      float& o0, float& o1, float& o2) {
  o0 = fabsf(m[0] * p0 + m[1] * p1 + m[2] * p2 + m[9] - g0);
  o1 = fabsf(m[3] * p0 + m[4] * p1 + m[5] * p2 + m[10] - g1);
  o2 = fabsf(m[6] * p0 + m[7] * p1 + m[8] * p2 + m[11] - g2);
}

__device__ __forceinline__ void xform_grp(const float* m, const float4 a0,
                                          const float4 a1, const float4 a2,
                                          const float4 c0, const float4 c1,
                                          const float4 c2, float4& r0,
                                          float4& r1, float4& r2) {
  xform(m, a0.x, a0.y, a0.z, c0.x, c0.y, c0.z, r0.x, r0.y, r0.z);
  xform(m, a0.w, a1.x, a1.y, c0.w, c1.x, c1.y, r0.w, r1.x, r1.y);
  xform(m, a1.z, a1.w, a2.x, c1.z, c1.w, c2.x, r1.z, r1.w, r2.x);
  xform(m, a2.y, a2.z, a2.w, c2.y, c2.z, c2.w, r2.y, r2.z, r2.w);
}

// fp32 Procrustes solve: sums s[16] -> params m[12] (M = scale*R, t).
__device__ __forceinline__ void solve_params(const float* s, float* pr) {
  const float Ninv = 1.0f / (float)NPTS;
  const float sp[3] = {s[0], s[1], s[2]};
  const float sg[3] = {s[3], s[4], s[5]};
  float mu1[3], mu2[3];
#pragma unroll
  for (int i = 0; i < 3; ++i) { mu1[i] = sp[i] * Ninv; mu2[i] = sg[i] * Ninv; }
  const float var1 =
      s[6] - (sp[0] * sp[0] + sp[1] * sp[1] + sp[2] * sp[2]) * Ninv;

  float K[3][3];
#pragma unroll
  for (int i = 0; i < 3; ++i)
#pragma unroll
    for (int j = 0; j < 3; ++j)
      K[i][j] = s[7 + 3 * i + j] - sp[i] * sg[j] * Ninv + 1e-8f;

  // A = K^T K (symmetric PSD), Jacobi eigendecomp -> V, eigenvalues.
  float A[3][3];
#pragma unroll
  for (int i = 0; i < 3; ++i)
#pragma unroll
    for (int j = 0; j < 3; ++j)
      A[i][j] = K[0][i] * K[0][j] + K[1][i] * K[1][j] + K[2][i] * K[2][j];

  float V[3][3] = {{1, 0, 0}, {0, 1, 0}, {0, 0, 1}};
  for (int sweep = 0; sweep < 10; ++sweep) {
    const float off =
        A[0][1] * A[0][1] + A[0][2] * A[0][2] + A[1][2] * A[1][2];
    const float nrm = A[0][0] + A[1][1] + A[2][2];
    if (off <= 1e-12f * nrm * nrm) break;
    for (int pq = 0; pq < 3; ++pq) {
      const int p = (pq == 2) ? 1 : 0;
      const int q = (pq == 0) ? 1 : 2;
      const float apq = A[p][q];
      if (apq == 0.0f) continue;
      const float theta = (A[q][q] - A[p][p]) / (2.0f * apq);
      const float tt = ((theta >= 0.0f) ? 1.0f : -1.0f) /
                       (fabsf(theta) + sqrtf(theta * theta + 1.0f));
      const float cj = 1.0f / sqrtf(tt * tt + 1.0f);
      const float sn = tt * cj;
      const float app = A[p][p], aqq = A[q][q];
      A[p][p] = app - tt * apq;
      A[q][q] = aqq + tt * apq;
      A[p][q] = 0.0f; A[q][p] = 0.0f;
      const int r = 3 - p - q;
      const float arp = A[r][p], arq = A[r][q];
      A[r][p] = cj * arp - sn * arq; A[p][r] = A[r][p];
      A[r][q] = sn * arp + cj * arq; A[q][r] = A[r][q];
#pragma unroll
      for (int k = 0; k < 3; ++k) {
        const float vkp = V[k][p], vkq = V[k][q];
        V[k][p] = cj * vkp - sn * vkq;
        V[k][q] = sn * vkp + cj * vkq;
      }
    }
  }

  float w[3] = {A[0][0], A[1][1], A[2][2]};
  int i0 = 0, i1 = 1, i2 = 2, tmp;
  if (w[i0] < w[i1]) { tmp = i0; i0 = i1; i1 = tmp; }
  if (w[i0] < w[i2]) { tmp = i0; i0 = i2; i2 = tmp; }
  if (w[i1] < w[i2]) { tmp = i1; i1 = i2; i2 = tmp; }
  const float sv0 = sqrtf(fmaxf(w[i0], 0.0f));
  const float sv1 = sqrtf(fmaxf(w[i1], 0.0f));
  const float sv2 = sqrtf(fmaxf(w[i2], 0.0f));

  const float detK =
      K[0][0] * (K[1][1] * K[2][2] - K[1][2] * K[2][1]) -
      K[0][1] * (K[1][0] * K[2][2] - K[1][2] * K[2][0]) +
      K[0][2] * (K[1][0] * K[2][1] - K[1][1] * K[2][0]);
  const float sgn = (detK > 0.0f) ? 1.0f : ((detK < 0.0f) ? -1.0f : 0.0f);

  const float floor0 = sv0 * 1e-6f + 1e-30f;  // keep R sane if near-singular
  const float z0 = 1.0f / fmaxf(sv0, floor0);
  const float z1 = 1.0f / fmaxf(sv1, floor0);
  const float z2 = sgn / fmaxf(sv2, floor0);

  float W[3][3];
#pragma unroll
  for (int a = 0; a < 3; ++a)
#pragma unroll
    for (int c = 0; c < 3; ++c)
      W[a][c] = V[a][i0] * V[c][i0] * z0 + V[a][i1] * V[c][i1] * z1 +
                V[a][i2] * V[c][i2] * z2;

  float R[3][3];
#pragma unroll
  for (int a = 0; a < 3; ++a)
#pragma unroll
    for (int c = 0; c < 3; ++c)
      R[a][c] = W[a][0] * K[c][0] + W[a][1] * K[c][1] + W[a][2] * K[c][2];

  const float trace = sv0 + sv1 + sgn * sv2;
  const float scale = trace / var1;

#pragma unroll
  for (int a = 0; a < 3; ++a) {
#pragma unroll
    for (int c = 0; c < 3; ++c) pr[3 * a + c] = scale * R[a][c];
    pr[9 + a] = mu2[a] - scale * (R[a][0] * mu1[0] + R[a][1] * mu1[1] +
                                  R[a][2] * mu1[2]);
  }
}

__global__ __launch_bounds__(512) void fused_kernel(
    const float* __restrict__ pred, const float* __restrict__ gt,
    float* __restrict__ out) {
  const int b = blockIdx.x;
  const int t = threadIdx.x;
  const size_t ofs0 = (size_t)b * FPB;
  const int skip = (b & 1) ? 2 : 0;            // points skipped at head
  const size_t ofs = ofs0 + (size_t)skip * 3;  // 16B-aligned float index
  const float4* __restrict__ p4 = (const float4*)(pred + ofs);
  const float4* __restrict__ g4 = (const float4*)(gt + ofs);
  float4* __restrict__ o4 = (float4*)(out + ofs);

  // Thread t owns float4s [12t, 12t+12): threads 0..429 full, 430 has 6,
  // 431..511 none. 12 % 3 == 0 keeps xyz phase aligned per 3-float4 group.
  const int base = 12 * t;
  const float4 z4 = make_float4(0.f, 0.f, 0.f, 0.f);

  float4 pc[12], gc[12];
#pragma unroll
  for (int j = 0; j < 12; ++j) {
    const bool v = (base + j) < FQ;
    pc[j] = v ? p4[base + j] : z4;
    gc[j] = v ? g4[base + j] : z4;
  }

  float acc[16];
#pragma unroll
  for (int i = 0; i < 16; ++i) acc[i] = 0.f;
#pragma unroll
  for (int g = 0; g < 4; ++g)
    accum_grp(acc, pc[3 * g], pc[3 * g + 1], pc[3 * g + 2],
              gc[3 * g], gc[3 * g + 1], gc[3 * g + 2]);  // zeros add nothing

  // 2 leftover points (head for odd b, tail for even b): thread 431.
  if (t == 431) {
    const int n0 = skip ? 0 : (NPTS - 2);
    const float* pp = pred + ofs0 + 3 * n0;
    const float* gg = gt + ofs0 + 3 * n0;
    accum(acc, pp[0], pp[1], pp[2], gg[0], gg[1], gg[2]);
    accum(acc, pp[3], pp[4], pp[5], gg[3], gg[4], gg[5]);
  }

  // Block reduction: wave64 butterfly then cross-wave via LDS.
#pragma unroll
  for (int i = 0; i < 16; ++i) {
#pragma unroll
    for (int off = 32; off > 0; off >>= 1)
      acc[i] += __shfl_down(acc[i], off, 64);
  }
  __shared__ float red[8][16];
  const int w = t >> 6, lane = t & 63;
  if (lane == 0) {
#pragma unroll
    for (int i = 0; i < 16; ++i) red[w][i] = acc[i];
  }
  __syncthreads();

  float s[16];
#pragma unroll
  for (int i = 0; i < 16; ++i) {
    float v = red[0][i];
#pragma unroll
    for (int ww = 1; ww < 8; ++ww) v += red[ww][i];
    s[i] = v;  // identical across all threads (LDS broadcast reads)
  }

  // Redundant per-thread solve (uniform data -> uniform branches).
  float m[12];
  solve_params(s, m);

  // Phase B: apply from cached registers, store.
#pragma unroll
  for (int g = 0; g < 4; ++g) {
    float4 r0, r1, r2;
    xform_grp(m, pc[3 * g], pc[3 * g + 1], pc[3 * g + 2],
              gc[3 * g], gc[3 * g + 1], gc[3 * g + 2], r0, r1, r2);
    if (base + 3 * g + 0 < FQ) o4[base + 3 * g + 0] = r0;
    if (base + 3 * g + 1 < FQ) o4[base + 3 * g + 1] = r1;
    if (base + 3 * g + 2 < FQ) o4[base + 3 * g + 2] = r2;
  }
  if (t == 431) {
    const int n0 = skip ? 0 : (NPTS - 2);
    const float* pp = pred + ofs0 + 3 * n0;  // L1/L2-hot (read in phase A)
    const float* gg = gt + ofs0 + 3 * n0;
    float* oo = out + ofs0 + 3 * n0;
    xform(m, pp[0], pp[1], pp[2], gg[0], gg[1], gg[2], oo[0], oo[1], oo[2]);
    xform(m, pp[3], pp[4], pp[5], gg[3], gg[4], gg[5], oo[3], oo[4], oo[5]);
  }
}

extern "C" void kernel_launch(void* const* d_in, const int* in_sizes, int n_in,
                              void* d_out, int out_size, void* d_ws, size_t ws_size,
                              hipStream_t stream) {
  const float* pred = (const float*)d_in[0];
  const float* gt   = (const float*)d_in[1];
  float* out = (float*)d_out;
  hipLaunchKernelGGL(fused_kernel, dim3(BATCH), dim3(512), 0, stream,
                     pred, gt, out);
}